// Round 18
// baseline (31.464 us; speedup 1.0000x reference)
//
#include <hip/hip_runtime.h>

// RFCN PSROI — r14 skeleton (3 launches); proj rebuilt around async
// global->LDS staging (guide §5 / Common-mistake #1):
//   out[b,n,g] = B'[g] + (1/denom) * sum_{bin} Z[b,g,h,w]
//   Z = einsum('bchw,gc->bghw', features, W'),  W'[g,c] = sum_k w[g*9+k, c]
// (1) fold weights -> Wred/Bred
// (2) proj: 256 blocks (1/CU) x 1024 thr; stage 256ch x 128px tile (128 KB)
//     into LDS via global_load_lds width=16 (fire-and-forget DMA, latency
//     paid once), then 16 waves = 8 ch-groups x 2 px-halves FMA from LDS,
//     7->1 LDS reduce (aliased over feature buffer after barrier).
// (3) per (b,g): 4-chunk sum + 2D prefix scan + proposal gather.
// No cross-block sync (r10: 261us, r12: 174us on 8 XCDs).

#define HW 4096      // 64*64
#define NG 25        // 21 cls + 4 reg groups
#define CIN 1024
#define B 2
#define NPROP 1000
#define NCH 4                 // channel chunks in workspace
#define CK (CIN / NCH)        // 256 channels per chunk
#define PX 128                // pixels per proj block
#define MHW (B * NG * HW)     // 204800: one partial chunk

// async 16B global->LDS transfer: lds dest = wave-uniform base + lane*16,
// global src per-lane. size must be a literal (guide m97).
__device__ __forceinline__ void gload_lds16(const float* g, float* l) {
    __builtin_amdgcn_global_load_lds(
        (const __attribute__((address_space(1))) void*)g,
        (__attribute__((address_space(3))) void*)l, 16, 0, 0);
}

// ---------------- Kernel 1: fold weights over the K*K=9 channel groups ----
__global__ void rfcn_wfold(const float* __restrict__ w_cls,
                           const float* __restrict__ b_cls,
                           const float* __restrict__ w_reg,
                           const float* __restrict__ b_reg,
                           float* __restrict__ Wred,   // [25][1024]
                           float* __restrict__ Bred) { // [25]
    int i = blockIdx.x * 256 + threadIdx.x;
    if (i < NG * CIN) {
        int g = i >> 10, c = i & (CIN - 1);
        float s = 0.f;
        if (g < 21) {
            #pragma unroll
            for (int k = 0; k < 9; ++k) s += w_cls[(size_t)(g * 9 + k) * CIN + c];
        } else {
            int gr = g - 21;
            #pragma unroll
            for (int k = 0; k < 9; ++k) s += w_reg[(size_t)(gr * 9 + k) * CIN + c];
        }
        Wred[i] = s;
    } else if (i < NG * CIN + NG) {
        int g = i - NG * CIN;
        float s = 0.f;
        if (g < 21) {
            #pragma unroll
            for (int k = 0; k < 9; ++k) s += b_cls[g * 9 + k];
        } else {
            #pragma unroll
            for (int k = 0; k < 9; ++k) s += b_reg[(g - 21) * 9 + k];
        }
        Bred[g] = s;
    }
}

// ---------------- Kernel 2: projection  Z_partial = W' x F ----------------
// grid = (32 px tiles, 4 chunks, B) = 256 blocks (1/CU), block = 1024.
// LDS 128 KB: smem[c][p] = feats[b, chunk*256+c, pix0+p], c<256, p<128.
// Stage: 128 segments of 1KB (2 channel-rows each); wave wv issues segments
// [wv*8, wv*8+8). Compute: wave wv -> s=wv>>1 (32-ch group), q=wv&1 (64-px
// half); thread owns pixel p=q*64+lane, 32 channels, all 25 groups.
// part layout: [chunk][b][g][4096]
__global__ __launch_bounds__(1024)
void rfcn_proj(const float* __restrict__ feats,
               const float* __restrict__ Wred,
               float* __restrict__ part) {
    const int t = threadIdx.x;
    const int lane = t & 63;
    const int wv = __builtin_amdgcn_readfirstlane(t >> 6);   // 0..15 (SGPR)
    const int pix0 = blockIdx.x * PX;
    const int chunk = blockIdx.y;
    const int b = blockIdx.z;

    __shared__ float smem[CK * PX];      // 256*128 floats = 128 KB

    // ---- stage: async DMA, 8 wave-instructions per wave, then one wait ----
    const float* fbase = feats + ((size_t)b * CIN + chunk * CK) * HW + pix0;
    #pragma unroll
    for (int i = 0; i < 8; ++i) {
        const int seg = wv * 8 + i;      // 0..127 -> channels 2seg, 2seg+1
        const float* g = fbase + (size_t)(2 * seg + (lane >> 5)) * HW
                       + (lane & 31) * 4;
        gload_lds16(g, smem + seg * 256);
    }
    asm volatile("s_waitcnt vmcnt(0)" ::: "memory");
    __syncthreads();

    // ---- compute from LDS ----
    const int s = wv >> 1;               // 0..7: channel group (32 ch)
    const int q = wv & 1;                // 0..1: pixel half (64 px)
    const int p = q * 64 + lane;         // 0..127
    const float* __restrict__ wgt = Wred + chunk * CK + s * 32; // wave-uniform

    float acc[NG];
    #pragma unroll
    for (int g = 0; g < NG; ++g) acc[g] = 0.f;

    #pragma unroll
    for (int cc = 0; cc < 32; cc += 8) {
        float fv[8];
        #pragma unroll
        for (int j = 0; j < 8; ++j)
            fv[j] = smem[(s * 32 + cc + j) * PX + p];   // stride-1 lanes
        #pragma unroll
        for (int j = 0; j < 8; ++j)
            #pragma unroll
            for (int g = 0; g < NG; ++g)
                acc[g] += fv[j] * wgt[g * CIN + cc + j];
    }
    __syncthreads();                     // all waves done reading features

    // ---- 8->1 reduce over channel groups (red aliases smem) ----
    float* red = smem;                   // [7][NG][PX] = 76.8 KB
    if (s > 0) {
        #pragma unroll
        for (int g = 0; g < NG; ++g) red[((s - 1) * NG + g) * PX + p] = acc[g];
    }
    __syncthreads();
    if (s == 0) {
        float* __restrict__ o =
            part + ((size_t)(chunk * B + b) * NG) * HW + pix0;
        #pragma unroll
        for (int g = 0; g < NG; ++g) {
            float v = acc[g];
            #pragma unroll
            for (int k = 0; k < 7; ++k) v += red[(k * NG + g) * PX + p];
            o[(size_t)g * HW + p] = v;
        }
    }
}

// ---------------- Kernel 3: 4-chunk sum + 2D prefix sum + gather -----------
// grid = 50 (m = b*25+g), block = 1024 (16 waves) — each wave scans 4 rows
// then 4 cols (independent 6-deep shfl chains).
// LDS 64x65: pad kills row-phase conflicts; col stride 65 == 1 (mod 32).
__global__ __launch_bounds__(1024)
void rfcn_integral_gather(const float* __restrict__ part,
                          const int* __restrict__ props,
                          const float* __restrict__ Bred,
                          float* __restrict__ out) {
    const int m = blockIdx.x;        // b*25 + g
    const int t = threadIdx.x;
    const int lane = t & 63;
    const int wave = t >> 6;         // 0..15
    const int b = m / NG;
    const int g = m - b * NG;        // block-uniform
    __shared__ float tile[64 * 65];

    // phase 1: sum the 4 partial chunks (16 independent coalesced loads)
    #pragma unroll
    for (int i = 0; i < 4; ++i) {
        const int idx = i * 1024 + t;
        float v[NCH];
        #pragma unroll
        for (int ch = 0; ch < NCH; ++ch)
            v[ch] = part[(size_t)(ch * (B * NG) + m) * HW + idx];
        #pragma unroll
        for (int off = NCH / 2; off >= 1; off >>= 1)
            #pragma unroll
            for (int j = 0; j < off; ++j) v[j] += v[j + off];
        tile[(idx >> 6) * 65 + (idx & 63)] = v[0];
    }
    __syncthreads();

    // phase 2: row scans — wave w owns rows [w*4, w*4+4), lane = column
    #pragma unroll
    for (int i = 0; i < 4; ++i) {
        const int row = wave * 4 + i;
        float v = tile[row * 65 + lane];
        #pragma unroll
        for (int d = 1; d < 64; d <<= 1) {
            float u = __shfl_up(v, (unsigned)d, 64);
            if (lane >= d) v += u;
        }
        tile[row * 65 + lane] = v;
    }
    __syncthreads();

    // phase 3: column scans — wave w owns cols [w*4, w*4+4), lane = row
    #pragma unroll
    for (int i = 0; i < 4; ++i) {
        const int col = wave * 4 + i;
        float v = tile[lane * 65 + col];
        #pragma unroll
        for (int d = 1; d < 64; d <<= 1) {
            float u = __shfl_up(v, (unsigned)d, 64);
            if (lane >= d) v += u;
        }
        tile[lane * 65 + col] = v;
    }
    __syncthreads();

    // phase 4: per-proposal 4-corner lookups straight from LDS
    const float bias = Bred[g];
    const int n = t;
    if (n < NPROP) {
        const int4 pr = ((const int4*)props)[b * NPROP + n];
        const int x1 = pr.x >> 5;            // floor(px/32), px >= 0
        const int y1 = pr.y >> 5;
        const int x2 = (pr.z + 31) >> 5;     // ceil
        const int y2 = (pr.w + 31) >> 5;
        const int wb = (x2 - x1 + 2) / 3;    // ceil((x2-x1)/3), >= 1
        const int hb = (y2 - y1 + 2) / 3;
        const int c2 = x1 + wb - 1;          // inclusive corner, <= 63
        const int r2 = y1 + hb - 1;

        float s = tile[r2 * 65 + c2];
        if (x1 > 0)           s -= tile[r2 * 65 + (x1 - 1)];
        if (y1 > 0)           s -= tile[(y1 - 1) * 65 + c2];
        if (x1 > 0 && y1 > 0) s += tile[(y1 - 1) * 65 + (x1 - 1)];
        const float v = bias + s / (float)(hb * wb);
        if (g < 21)  // block-uniform branch
            out[(size_t)(b * NPROP + n) * 21 + g] = v;
        else
            out[(size_t)(B * NPROP * 21) + (size_t)(b * NPROP + n) * 4 + (g - 21)] = v;
    }
}

extern "C" void kernel_launch(void* const* d_in, const int* in_sizes, int n_in,
                              void* d_out, int out_size, void* d_ws, size_t ws_size,
                              hipStream_t stream) {
    const float* feats = (const float*)d_in[0];  // [2,1024,64,64]
    const float* w_cls = (const float*)d_in[1];  // [189,1024]
    const float* b_cls = (const float*)d_in[2];  // [189]
    const float* w_reg = (const float*)d_in[3];  // [36,1024]
    const float* b_reg = (const float*)d_in[4];  // [36]
    const int*   props = (const int*)d_in[5];    // [2,1000,4]
    float* out = (float*)d_out;
    float* ws  = (float*)d_ws;

    // workspace layout (floats): ~3.4 MB total
    float* Wred = ws;                        // 25600
    float* Bred = ws + 25600;                // 25 (next region 128B-aligned)
    float* part = ws + 25632;                // 4 * 204800

    rfcn_wfold<<<(NG * CIN + NG + 255) / 256, 256, 0, stream>>>(
        w_cls, b_cls, w_reg, b_reg, Wred, Bred);
    rfcn_proj<<<dim3(HW / PX, NCH, B), 1024, 0, stream>>>(feats, Wred, part);
    rfcn_integral_gather<<<B * NG, 1024, 0, stream>>>(part, props, Bred, out);
}